// Round 5
// baseline (694.828 us; speedup 1.0000x reference)
//
#include <hip/hip_runtime.h>
#include <cstdint>
#include <cstddef>

// Problem constants (shapes fixed by the reference)
#define F_IN   128
#define HC1    64    // heads1*ch1 = 8*8
#define CH2_   16
#define NB     64    // batch graphs

__global__ void fill_f32(float* __restrict__ p, float v, int n) {
  int i = blockIdx.x * blockDim.x + threadIdx.x;
  int stride = gridDim.x * blockDim.x;
  for (; i < n; i += stride) p[i] = v;
}

// ---------------- DPP cross-lane reductions (full-rate VALU, no LDS pipe) -----
// ctrl: 0xB1 = quad_perm(1,0,3,2) = xor1 ; 0x4E = quad_perm(2,3,0,1) = xor2
// 0x141 = row_half_mirror (combines the two quads of each 8-group)
// 0x140 = row_mirror      (combines the two 8-halves of each 16-row)
template<int CTRL>
__device__ __forceinline__ float dpp_add(float v) {
  int j = __builtin_amdgcn_update_dpp(0, __float_as_int(v), CTRL, 0xF, 0xF, true);
  return v + __int_as_float(j);
}
__device__ __forceinline__ float sum8_dpp(float v) {   // sum over each 8-lane group
  v = dpp_add<0xB1>(v);
  v = dpp_add<0x4E>(v);
  v = dpp_add<0x141>(v);
  return v;
}
__device__ __forceinline__ float sum16_dpp(float v) {  // sum over each 16-lane row
  v = dpp_add<0xB1>(v);
  v = dpp_add<0x4E>(v);
  v = dpp_add<0x141>(v);
  v = dpp_add<0x140>(v);
  return v;
}

// ---------------- Layer-1 dual GEMM (M=64): unchanged from round 4 ------------
// W reads are wave-coalesced 256B (M=64); writes are 256B contiguous per wave.
template<int K, int M, int BM, bool PAD>
__global__ void gemm_dual(const float* __restrict__ x,
                          const float* __restrict__ Wa, const float* __restrict__ ba,
                          const float* __restrict__ Wb, const float* __restrict__ bb,
                          float* __restrict__ ya, float* __restrict__ yb, int n) {
  constexpr int KP = PAD ? K + 4 : K;
  constexpr int GROUPS = 256 / M;
  constexpr int NN = BM / GROUPS;
  __shared__ float xs[BM * KP];
  const int t = threadIdx.x;
  const int node0 = blockIdx.x * BM;
  for (int i = t; i < BM * (K / 4); i += 256) {
    int row = i / (K / 4);
    int kk  = (i % (K / 4)) * 4;
    int node = node0 + row;
    float4 v = make_float4(0.f, 0.f, 0.f, 0.f);
    if (node < n) v = *reinterpret_cast<const float4*>(x + (size_t)node * K + kk);
    *reinterpret_cast<float4*>(xs + row * KP + kk) = v;
  }
  __syncthreads();
  const int col = t % M;
  const int ng  = t / M;
  float accA[NN], accB[NN];
  const float biasA = ba[col], biasB = bb[col];
#pragma unroll
  for (int i = 0; i < NN; ++i) { accA[i] = biasA; accB[i] = biasB; }
  for (int k = 0; k < K; k += 4) {
    float wa0 = Wa[(k + 0) * M + col], wa1 = Wa[(k + 1) * M + col];
    float wa2 = Wa[(k + 2) * M + col], wa3 = Wa[(k + 3) * M + col];
    float wb0 = Wb[(k + 0) * M + col], wb1 = Wb[(k + 1) * M + col];
    float wb2 = Wb[(k + 2) * M + col], wb3 = Wb[(k + 3) * M + col];
#pragma unroll
    for (int nn = 0; nn < NN; ++nn) {
      float4 xv = *reinterpret_cast<const float4*>(xs + (ng * NN + nn) * KP + k);
      accA[nn] += xv.x * wa0 + xv.y * wa1 + xv.z * wa2 + xv.w * wa3;
      accB[nn] += xv.x * wb0 + xv.y * wb1 + xv.z * wb2 + xv.w * wb3;
    }
  }
#pragma unroll
  for (int nn = 0; nn < NN; ++nn) {
    int node = node0 + ng * NN + nn;
    if (node < n) {
      ya[(size_t)node * M + col] = accA[nn];
      yb[(size_t)node * M + col] = accB[nn];
    }
  }
}

// ---------------- Layer-2 dual GEMM (M=16): LDS-staged W, combined output -----
// Output yab[N][32] = [xl(0..15) | xr(16..31)]. Node map node0+nn*8+ng makes
// each wave's store per nn one contiguous 256B line (2 nodes x 32 cols).
// W+biases staged in LDS (8KB) -> no lane-redundant global W reads.
__global__ void gemm_dual2(const float* __restrict__ x,  // [n][64]
                           const float* __restrict__ Wa, const float* __restrict__ ba,
                           const float* __restrict__ Wb, const float* __restrict__ bb,
                           float* __restrict__ yab, int n) {
  constexpr int K = 64, BM = 64, NN = 8;
  __shared__ float xs[BM * K];     // 16 KB
  __shared__ float Wab[K * 32];    // 8 KB
  __shared__ float bab[32];
  const int t = threadIdx.x;
  const int node0 = blockIdx.x * BM;
  for (int i = t; i < K * 16; i += 256) {     // W coalesced from global
    int k = i / 16, j = i % 16;
    Wab[k * 32 + j]      = Wa[i];
    Wab[k * 32 + 16 + j] = Wb[i];
  }
  if (t < 16) { bab[t] = ba[t]; bab[16 + t] = bb[t]; }
  for (int i = t; i < BM * (K / 4); i += 256) {
    int row = i / (K / 4);
    int kk  = (i % (K / 4)) * 4;
    int node = node0 + row;
    float4 v = make_float4(0.f, 0.f, 0.f, 0.f);
    if (node < n) v = *reinterpret_cast<const float4*>(x + (size_t)node * K + kk);
    *reinterpret_cast<float4*>(xs + row * K + kk) = v;
  }
  __syncthreads();
  const int col = t & 31;    // 0-15 -> A-col, 16-31 -> B-col
  const int ng  = t >> 5;    // 8 node-groups
  float acc[NN];
#pragma unroll
  for (int i = 0; i < NN; ++i) acc[i] = 0.0f;
  for (int k = 0; k < K; k += 4) {
    float w0 = Wab[(k + 0) * 32 + col];
    float w1 = Wab[(k + 1) * 32 + col];
    float w2 = Wab[(k + 2) * 32 + col];
    float w3 = Wab[(k + 3) * 32 + col];
#pragma unroll
    for (int nn = 0; nn < NN; ++nn) {
      float4 xv = *reinterpret_cast<const float4*>(xs + (nn * 8 + ng) * K + k);
      acc[nn] += xv.x * w0 + xv.y * w1 + xv.z * w2 + xv.w * w3;
    }
  }
  const float bias = bab[col];
#pragma unroll
  for (int nn = 0; nn < NN; ++nn) {
    int node = node0 + nn * 8 + ng;
    if (node < n) yab[(size_t)node * 32 + col] = acc[nn] + bias;
  }
}

// ---------------- CSR build (by destination), rebuilt every call --------------

__global__ void hist_kernel(const int* __restrict__ ei, int E, int E2,
                            int* __restrict__ deg) {
  int e = blockIdx.x * blockDim.x + threadIdx.x;
  if (e >= E2) return;
  int d = (e < E) ? ei[E + e] : (e - E);
  atomicAdd(&deg[d], 1);
}

__global__ void scan_partials(const int* __restrict__ deg, int* __restrict__ part, int n) {
  __shared__ int sh[256];
  int t = threadIdx.x;
  int i = blockIdx.x * 256 + t;
  sh[t] = (i < n) ? deg[i] : 0;
  __syncthreads();
  for (int off = 128; off > 0; off >>= 1) {
    if (t < off) sh[t] += sh[t + off];
    __syncthreads();
  }
  if (t == 0) part[blockIdx.x] = sh[0];
}

__global__ void scan_block(int* __restrict__ part, int nblk,
                           int* __restrict__ row_start, int n) {
  int lane = threadIdx.x;  // 64 threads
  int carry = 0;
  for (int base = 0; base < nblk; base += 64) {
    int i = base + lane;
    int orig = (i < nblk) ? part[i] : 0;
    int v = orig;
    for (int off = 1; off < 64; off <<= 1) {
      int u = __shfl_up(v, off);
      if (lane >= off) v += u;
    }
    if (i < nblk) part[i] = carry + (v - orig);
    carry += __shfl(v, 63);
  }
  if (lane == 0) row_start[n] = carry;  // == E2
}

__global__ void scan_final(const int* __restrict__ deg, const int* __restrict__ part,
                           int* __restrict__ row_start, int n) {
  __shared__ int sh[256];
  int t = threadIdx.x;
  int i = blockIdx.x * 256 + t;
  int v = (i < n) ? deg[i] : 0;
  sh[t] = v;
  __syncthreads();
  for (int off = 1; off < 256; off <<= 1) {
    int u = (t >= off) ? sh[t - off] : 0;
    __syncthreads();
    sh[t] += u;
    __syncthreads();
  }
  if (i < n) row_start[i] = part[blockIdx.x] + sh[t] - v;
}

__global__ void scatter_kernel(const int* __restrict__ ei, int E, int E2,
                               const int* __restrict__ row_start,
                               int* __restrict__ cnt, int* __restrict__ csr_src) {
  int e = blockIdx.x * blockDim.x + threadIdx.x;
  if (e >= E2) return;
  int s, d;
  if (e < E) { s = ei[e]; d = ei[E + e]; } else { s = d = e - E; }
  int pos = row_start[d] + atomicAdd(&cnt[d], 1);
  csr_src[pos] = s;
}

// ---------------- Fused GATv2 layers: CSR + online softmax --------------------

// Layer 1: heads=8 ch=8; one wave per node, lane = h*8+c
__global__ void fused_layer1(const int* __restrict__ row_start, const int* __restrict__ csr_src,
                             const float* __restrict__ xl, const float* __restrict__ xr,
                             const float* __restrict__ att, const float* __restrict__ bias,
                             float* __restrict__ out, int n) {
  int node = blockIdx.x * 4 + (threadIdx.x >> 6);
  if (node >= n) return;
  int lane = threadIdx.x & 63;
  const float attv = att[lane];
  const float xrv  = xr[(size_t)node * 64 + lane];
  const int beg = row_start[node], end = row_start[node + 1];
  float m = -__builtin_huge_valf();
  float den = 0.0f, acc = 0.0f;
  int p = beg;
  for (; p + 4 <= end; p += 4) {
    int s0 = csr_src[p + 0], s1 = csr_src[p + 1];
    int s2 = csr_src[p + 2], s3 = csr_src[p + 3];
    float x0 = xl[(size_t)s0 * 64 + lane];
    float x1 = xl[(size_t)s1 * 64 + lane];
    float x2 = xl[(size_t)s2 * 64 + lane];
    float x3 = xl[(size_t)s3 * 64 + lane];
    float a0 = x0 + xrv; a0 = a0 > 0.f ? a0 : 0.2f * a0;
    float a1 = x1 + xrv; a1 = a1 > 0.f ? a1 : 0.2f * a1;
    float a2 = x2 + xrv; a2 = a2 > 0.f ? a2 : 0.2f * a2;
    float a3 = x3 + xrv; a3 = a3 > 0.f ? a3 : 0.2f * a3;
    float v0 = sum8_dpp(a0 * attv);
    float v1 = sum8_dpp(a1 * attv);
    float v2 = sum8_dpp(a2 * attv);
    float v3 = sum8_dpp(a3 * attv);
    float nm = fmaxf(m, fmaxf(fmaxf(v0, v1), fmaxf(v2, v3)));
    float scale = __expf(m - nm);          // first chunk: exp(-inf)=0
    float e0 = __expf(v0 - nm), e1 = __expf(v1 - nm);
    float e2 = __expf(v2 - nm), e3 = __expf(v3 - nm);
    den = den * scale + ((e0 + e1) + (e2 + e3));
    acc = acc * scale + ((e0 * x0 + e1 * x1) + (e2 * x2 + e3 * x3));
    m = nm;
  }
  for (; p < end; ++p) {
    int s = csr_src[p];
    float xv = xl[(size_t)s * 64 + lane];
    float a = xv + xrv; a = a > 0.f ? a : 0.2f * a;
    float v = sum8_dpp(a * attv);
    float nm = fmaxf(m, v);
    float scale = __expf(m - nm);
    float ex = __expf(v - nm);
    den = den * scale + ex;
    acc = acc * scale + ex * xv;
    m = nm;
  }
  float o = acc / (den + 1e-16f) + bias[lane];
  out[(size_t)node * 64 + lane] = o > 0.0f ? o : (__expf(o) - 1.0f);  // elu
}

// Layer 2: heads=1 ch=16; combined input layout xlxr[N][32] = [xl|xr]
__global__ void fused_layer2(const int* __restrict__ row_start, const int* __restrict__ csr_src,
                             const float* __restrict__ xlxr,
                             const float* __restrict__ att, const float* __restrict__ bias,
                             float* __restrict__ out, int n) {
  int node = blockIdx.x * 16 + (threadIdx.x >> 4);
  if (node >= n) return;
  int c = threadIdx.x & 15;
  const float attv = att[c];
  const float xrv  = xlxr[(size_t)node * 32 + 16 + c];
  const int beg = row_start[node], end = row_start[node + 1];
  float m = -__builtin_huge_valf();
  float den = 0.0f, acc = 0.0f;
  int p = beg;
  for (; p + 4 <= end; p += 4) {
    int s0 = csr_src[p + 0], s1 = csr_src[p + 1];
    int s2 = csr_src[p + 2], s3 = csr_src[p + 3];
    float x0 = xlxr[(size_t)s0 * 32 + c];
    float x1 = xlxr[(size_t)s1 * 32 + c];
    float x2 = xlxr[(size_t)s2 * 32 + c];
    float x3 = xlxr[(size_t)s3 * 32 + c];
    float a0 = x0 + xrv; a0 = a0 > 0.f ? a0 : 0.2f * a0;
    float a1 = x1 + xrv; a1 = a1 > 0.f ? a1 : 0.2f * a1;
    float a2 = x2 + xrv; a2 = a2 > 0.f ? a2 : 0.2f * a2;
    float a3 = x3 + xrv; a3 = a3 > 0.f ? a3 : 0.2f * a3;
    float v0 = sum16_dpp(a0 * attv);
    float v1 = sum16_dpp(a1 * attv);
    float v2 = sum16_dpp(a2 * attv);
    float v3 = sum16_dpp(a3 * attv);
    float nm = fmaxf(m, fmaxf(fmaxf(v0, v1), fmaxf(v2, v3)));
    float scale = __expf(m - nm);
    float e0 = __expf(v0 - nm), e1 = __expf(v1 - nm);
    float e2 = __expf(v2 - nm), e3 = __expf(v3 - nm);
    den = den * scale + ((e0 + e1) + (e2 + e3));
    acc = acc * scale + ((e0 * x0 + e1 * x1) + (e2 * x2 + e3 * x3));
    m = nm;
  }
  for (; p < end; ++p) {
    int s = csr_src[p];
    float xv = xlxr[(size_t)s * 32 + c];
    float a = xv + xrv; a = a > 0.f ? a : 0.2f * a;
    float v = sum16_dpp(a * attv);
    float nm = fmaxf(m, v);
    float scale = __expf(m - nm);
    float ex = __expf(v - nm);
    den = den * scale + ex;
    acc = acc * scale + ex * xv;
    m = nm;
  }
  out[(size_t)node * 16 + c] = acc / (den + 1e-16f) + bias[c];   // no elu after conv2
}

// ---------------- Pooling + classifier ---------------------------------------

__global__ void pool_kernel(const float* __restrict__ h2, const int* __restrict__ batch,
                            float* __restrict__ sums, float* __restrict__ cnts, int n) {
  __shared__ float ls[NB * CH2_];
  __shared__ float lc[NB];
  for (int i = threadIdx.x; i < NB * CH2_; i += blockDim.x) ls[i] = 0.0f;
  for (int i = threadIdx.x; i < NB; i += blockDim.x) lc[i] = 0.0f;
  __syncthreads();
  int total = n * 16;
  int stride = gridDim.x * blockDim.x;
  for (int i = blockIdx.x * blockDim.x + threadIdx.x; i < total; i += stride) {
    int node = i >> 4, c = i & 15;
    int b = batch[node];
    atomicAdd(&ls[b * 16 + c], h2[i]);
    if (c == 0) atomicAdd(&lc[b], 1.0f);
  }
  __syncthreads();
  for (int i = threadIdx.x; i < NB * CH2_; i += blockDim.x)
    if (ls[i] != 0.0f) atomicAdd(&sums[i], ls[i]);
  for (int i = threadIdx.x; i < NB; i += blockDim.x)
    if (lc[i] != 0.0f) atomicAdd(&cnts[i], lc[i]);
}

__global__ void classifier(const float* __restrict__ sums, const float* __restrict__ cnts,
                           const float* __restrict__ Wc, const float* __restrict__ bc,
                           float* __restrict__ out) {
  int b = threadIdx.x;
  if (b >= NB) return;
  float cnt = cnts[b];
  cnt = cnt > 1.0f ? cnt : 1.0f;
  float acc = 0.0f;
  for (int c = 0; c < 16; ++c) {
    float p = sums[b * 16 + c] / cnt;
    out[NB + b * 16 + c] = p;   // pooled, output 1
    acc += p * Wc[c];
  }
  out[b] = acc + bc[0];         // out, output 0
}

extern "C" void kernel_launch(void* const* d_in, const int* in_sizes, int n_in,
                              void* d_out, int out_size, void* d_ws, size_t ws_size,
                              hipStream_t stream) {
  const float* x     = (const float*)d_in[0];
  const int*   ei    = (const int*)d_in[1];
  const int*   batch = (const int*)d_in[2];
  const float* Wl1   = (const float*)d_in[3];
  const float* bl1   = (const float*)d_in[4];
  const float* Wr1   = (const float*)d_in[5];
  const float* br1   = (const float*)d_in[6];
  const float* att1  = (const float*)d_in[7];
  const float* bias1 = (const float*)d_in[8];
  const float* Wl2   = (const float*)d_in[9];
  const float* bl2   = (const float*)d_in[10];
  const float* Wr2   = (const float*)d_in[11];
  const float* br2   = (const float*)d_in[12];
  const float* att2  = (const float*)d_in[13];
  const float* bias2 = (const float*)d_in[14];
  const float* Wc    = (const float*)d_in[15];
  const float* bc    = (const float*)d_in[16];
  float* out = (float*)d_out;

  const int N  = in_sizes[0] / F_IN;
  const int E  = in_sizes[1] / 2;
  const int E2 = E + N;
  const int nblk = (N + 255) / 256;

  // Workspace layout
  float* base = (float*)d_ws;
  float* xl1  = base;                          // N*64
  float* xr1  = xl1 + (size_t)N * 64;          // N*64
  float* h1   = xr1 + (size_t)N * 64;          // N*64
  int* ideg   = (int*)(h1 + (size_t)N * 64);   // N
  int* icnt   = ideg + N;                      // N
  int* irow   = icnt + N;                      // N+1
  int* ipart  = irow + (N + 1);                // nblk
  int* icsr   = ipart + ((nblk + 63) & ~63);   // E2
  float* sums = (float*)(icsr + E2);           // NB*16
  float* cnts = sums + NB * CH2_;              // NB
  // layer-2 overlays on xl1 region (dead after fused_layer1 feeds h1)
  float* xlxr2 = xl1;                          // N*32 combined [xl|xr]
  float* h2    = xl1 + (size_t)N * 32;         // N*16

  // ---- CSR build (shared by both layers) ----
  fill_f32<<<256, 256, 0, stream>>>((float*)ideg, 0.0f, 2 * N);   // deg + cnt = 0
  hist_kernel<<<(E2 + 255) / 256, 256, 0, stream>>>(ei, E, E2, ideg);
  scan_partials<<<nblk, 256, 0, stream>>>(ideg, ipart, N);
  scan_block<<<1, 64, 0, stream>>>(ipart, nblk, irow, N);
  scan_final<<<nblk, 256, 0, stream>>>(ideg, ipart, irow, N);
  scatter_kernel<<<(E2 + 255) / 256, 256, 0, stream>>>(ei, E, E2, irow, icnt, icsr);

  // ---- layer 1 ----
  gemm_dual<F_IN, HC1, 64, false><<<(N + 63) / 64, 256, 0, stream>>>(
      x, Wl1, bl1, Wr1, br1, xl1, xr1, N);
  fused_layer1<<<(N + 3) / 4, 256, 0, stream>>>(irow, icsr, xl1, xr1, att1, bias1, h1, N);

  // ---- layer 2 ----
  gemm_dual2<<<(N + 63) / 64, 256, 0, stream>>>(h1, Wl2, bl2, Wr2, br2, xlxr2, N);
  fused_layer2<<<(N + 15) / 16, 256, 0, stream>>>(irow, icsr, xlxr2, att2, bias2, h2, N);

  // ---- pooling + classifier ----
  fill_f32<<<4, 256, 0, stream>>>(sums, 0.0f, NB * CH2_ + NB);
  pool_kernel<<<256, 256, 0, stream>>>(h2, batch, sums, cnts, N);
  classifier<<<1, 64, 0, stream>>>(sums, cnts, Wc, bc, out);
}

// Round 6
// 426.381 us; speedup vs baseline: 1.6296x; 1.6296x over previous
//
#include <hip/hip_runtime.h>
#include <cstdint>
#include <cstddef>

// Problem constants (shapes fixed by the reference)
#define F_IN   128
#define HC1    64    // heads1*ch1 = 8*8
#define CH2_   16
#define NB     64    // batch graphs

__global__ void fill_f32(float* __restrict__ p, float v, int n) {
  int i = blockIdx.x * blockDim.x + threadIdx.x;
  int stride = gridDim.x * blockDim.x;
  for (; i < n; i += stride) p[i] = v;
}

// ---------------- DPP cross-lane reductions (full-rate VALU, no LDS pipe) -----
template<int CTRL>
__device__ __forceinline__ float dpp_add(float v) {
  int j = __builtin_amdgcn_update_dpp(0, __float_as_int(v), CTRL, 0xF, 0xF, true);
  return v + __int_as_float(j);
}
__device__ __forceinline__ float sum8_dpp(float v) {   // sum over each 8-lane group
  v = dpp_add<0xB1>(v);   // quad_perm xor1
  v = dpp_add<0x4E>(v);   // quad_perm xor2
  v = dpp_add<0x141>(v);  // row_half_mirror
  return v;
}
__device__ __forceinline__ float sum16_dpp(float v) {  // sum over each 16-lane row
  v = dpp_add<0xB1>(v);
  v = dpp_add<0x4E>(v);
  v = dpp_add<0x141>(v);
  v = dpp_add<0x140>(v);  // row_mirror
  return v;
}

// ---------------- Layer-1 dual GEMM (M=64): known-good round-4 version --------
// W reads wave-coalesced 256B (M=64); each wave-store is 256B contiguous.
template<int K, int M, int BM, bool PAD>
__global__ void gemm_dual(const float* __restrict__ x,
                          const float* __restrict__ Wa, const float* __restrict__ ba,
                          const float* __restrict__ Wb, const float* __restrict__ bb,
                          float* __restrict__ ya, float* __restrict__ yb, int n) {
  constexpr int KP = PAD ? K + 4 : K;
  constexpr int GROUPS = 256 / M;
  constexpr int NN = BM / GROUPS;
  __shared__ float xs[BM * KP];
  const int t = threadIdx.x;
  const int node0 = blockIdx.x * BM;
  for (int i = t; i < BM * (K / 4); i += 256) {
    int row = i / (K / 4);
    int kk  = (i % (K / 4)) * 4;
    int node = node0 + row;
    float4 v = make_float4(0.f, 0.f, 0.f, 0.f);
    if (node < n) v = *reinterpret_cast<const float4*>(x + (size_t)node * K + kk);
    *reinterpret_cast<float4*>(xs + row * KP + kk) = v;
  }
  __syncthreads();
  const int col = t % M;
  const int ng  = t / M;
  float accA[NN], accB[NN];
  const float biasA = ba[col], biasB = bb[col];
#pragma unroll
  for (int i = 0; i < NN; ++i) { accA[i] = biasA; accB[i] = biasB; }
  for (int k = 0; k < K; k += 4) {
    float wa0 = Wa[(k + 0) * M + col], wa1 = Wa[(k + 1) * M + col];
    float wa2 = Wa[(k + 2) * M + col], wa3 = Wa[(k + 3) * M + col];
    float wb0 = Wb[(k + 0) * M + col], wb1 = Wb[(k + 1) * M + col];
    float wb2 = Wb[(k + 2) * M + col], wb3 = Wb[(k + 3) * M + col];
#pragma unroll
    for (int nn = 0; nn < NN; ++nn) {
      float4 xv = *reinterpret_cast<const float4*>(xs + (ng * NN + nn) * KP + k);
      accA[nn] += xv.x * wa0 + xv.y * wa1 + xv.z * wa2 + xv.w * wa3;
      accB[nn] += xv.x * wb0 + xv.y * wb1 + xv.z * wb2 + xv.w * wb3;
    }
  }
#pragma unroll
  for (int nn = 0; nn < NN; ++nn) {
    int node = node0 + ng * NN + nn;
    if (node < n) {
      ya[(size_t)node * M + col] = accA[nn];
      yb[(size_t)node * M + col] = accB[nn];
    }
  }
}

// ---------------- CSR build (by destination), rebuilt every call --------------

__global__ void hist_kernel(const int* __restrict__ ei, int E, int E2,
                            int* __restrict__ deg) {
  int e = blockIdx.x * blockDim.x + threadIdx.x;
  if (e >= E2) return;
  int d = (e < E) ? ei[E + e] : (e - E);
  atomicAdd(&deg[d], 1);
}

__global__ void scan_partials(const int* __restrict__ deg, int* __restrict__ part, int n) {
  __shared__ int sh[256];
  int t = threadIdx.x;
  int i = blockIdx.x * 256 + t;
  sh[t] = (i < n) ? deg[i] : 0;
  __syncthreads();
  for (int off = 128; off > 0; off >>= 1) {
    if (t < off) sh[t] += sh[t + off];
    __syncthreads();
  }
  if (t == 0) part[blockIdx.x] = sh[0];
}

__global__ void scan_block(int* __restrict__ part, int nblk,
                           int* __restrict__ row_start, int n) {
  int lane = threadIdx.x;  // 64 threads
  int carry = 0;
  for (int base = 0; base < nblk; base += 64) {
    int i = base + lane;
    int orig = (i < nblk) ? part[i] : 0;
    int v = orig;
    for (int off = 1; off < 64; off <<= 1) {
      int u = __shfl_up(v, off);
      if (lane >= off) v += u;
    }
    if (i < nblk) part[i] = carry + (v - orig);
    carry += __shfl(v, 63);
  }
  if (lane == 0) row_start[n] = carry;  // == E2
}

__global__ void scan_final(const int* __restrict__ deg, const int* __restrict__ part,
                           int* __restrict__ row_start, int n) {
  __shared__ int sh[256];
  int t = threadIdx.x;
  int i = blockIdx.x * 256 + t;
  int v = (i < n) ? deg[i] : 0;
  sh[t] = v;
  __syncthreads();
  for (int off = 1; off < 256; off <<= 1) {
    int u = (t >= off) ? sh[t - off] : 0;
    __syncthreads();
    sh[t] += u;
    __syncthreads();
  }
  if (i < n) row_start[i] = part[blockIdx.x] + sh[t] - v;
}

__global__ void scatter_kernel(const int* __restrict__ ei, int E, int E2,
                               const int* __restrict__ row_start,
                               int* __restrict__ cnt, int* __restrict__ csr_src) {
  int e = blockIdx.x * blockDim.x + threadIdx.x;
  if (e >= E2) return;
  int s, d;
  if (e < E) { s = ei[e]; d = ei[E + e]; } else { s = d = e - E; }
  int pos = row_start[d] + atomicAdd(&cnt[d], 1);
  csr_src[pos] = s;
}

// ---------------- Fused layer 1 + layer-2 linear transforms -------------------
// GATv2 (heads=8, ch=8): one wave per node, lane = h*8+c; online softmax, DPP
// logits, 4x unrolled gathers. Epilogue: h1[node][lane] lives in registers
// (one lane per column), so xl2/xr2 = h1 @ Wl2/Wr2 are computed in-wave via a
// 32-step shfl-broadcast dot (halves split l=0..31 / 32..63, one xor-32
// combine). This removes the N*64->N*32 GEMM pass entirely (round-4/5 profiles
// showed 20-50x unexplained TCC traffic amplification on that pass in two
// different formulations).
__global__ void fused_layer1(const int* __restrict__ row_start, const int* __restrict__ csr_src,
                             const float* __restrict__ xl, const float* __restrict__ xr,
                             const float* __restrict__ att, const float* __restrict__ bias,
                             const float* __restrict__ Wl2, const float* __restrict__ bl2,
                             const float* __restrict__ Wr2, const float* __restrict__ br2,
                             float* __restrict__ xl2, float* __restrict__ xr2, int n) {
  __shared__ float Ws2[64 * 32];   // [l][j]: j<16 -> Wl2 col j, j>=16 -> Wr2 col j-16
  __shared__ float b2s[32];
  const int t = threadIdx.x;
  for (int i = t; i < 64 * 16; i += 256) {
    int l = i >> 4, j = i & 15;
    Ws2[l * 32 + j]      = Wl2[i];
    Ws2[l * 32 + 16 + j] = Wr2[i];
  }
  if (t < 16) { b2s[t] = bl2[t]; b2s[16 + t] = br2[t]; }
  __syncthreads();

  int node = blockIdx.x * 4 + (t >> 6);
  if (node >= n) return;
  int lane = t & 63;
  const float attv = att[lane];
  const float xrv  = xr[(size_t)node * 64 + lane];
  const int beg = row_start[node], end = row_start[node + 1];
  float m = -__builtin_huge_valf();
  float den = 0.0f, acc = 0.0f;
  int p = beg;
  for (; p + 4 <= end; p += 4) {
    int s0 = csr_src[p + 0], s1 = csr_src[p + 1];
    int s2 = csr_src[p + 2], s3 = csr_src[p + 3];
    float x0 = xl[(size_t)s0 * 64 + lane];
    float x1 = xl[(size_t)s1 * 64 + lane];
    float x2 = xl[(size_t)s2 * 64 + lane];
    float x3 = xl[(size_t)s3 * 64 + lane];
    float a0 = x0 + xrv; a0 = a0 > 0.f ? a0 : 0.2f * a0;
    float a1 = x1 + xrv; a1 = a1 > 0.f ? a1 : 0.2f * a1;
    float a2 = x2 + xrv; a2 = a2 > 0.f ? a2 : 0.2f * a2;
    float a3 = x3 + xrv; a3 = a3 > 0.f ? a3 : 0.2f * a3;
    float v0 = sum8_dpp(a0 * attv);
    float v1 = sum8_dpp(a1 * attv);
    float v2 = sum8_dpp(a2 * attv);
    float v3 = sum8_dpp(a3 * attv);
    float nm = fmaxf(m, fmaxf(fmaxf(v0, v1), fmaxf(v2, v3)));
    float scale = __expf(m - nm);          // first chunk: exp(-inf)=0
    float e0 = __expf(v0 - nm), e1 = __expf(v1 - nm);
    float e2 = __expf(v2 - nm), e3 = __expf(v3 - nm);
    den = den * scale + ((e0 + e1) + (e2 + e3));
    acc = acc * scale + ((e0 * x0 + e1 * x1) + (e2 * x2 + e3 * x3));
    m = nm;
  }
  for (; p < end; ++p) {
    int s = csr_src[p];
    float xv = xl[(size_t)s * 64 + lane];
    float a = xv + xrv; a = a > 0.f ? a : 0.2f * a;
    float v = sum8_dpp(a * attv);
    float nm = fmaxf(m, v);
    float scale = __expf(m - nm);
    float ex = __expf(v - nm);
    den = den * scale + ex;
    acc = acc * scale + ex * xv;
    m = nm;
  }
  float o = acc / (den + 1e-16f) + bias[lane];
  o = o > 0.0f ? o : (__expf(o) - 1.0f);   // elu -> h1 value for col=lane

  // ---- in-wave layer-2 transforms: out[j] = sum_l o_l * Ws2[l][j] ----
  const int j    = lane & 31;
  const int half = lane >> 5;              // 0: l=0..31, 1: l=32..63
  float part = 0.0f;
#pragma unroll 8
  for (int l = 0; l < 32; ++l) {
    int src = half * 32 + l;
    float ov = __shfl(o, src);
    part += ov * Ws2[src * 32 + j];
  }
  part += __shfl_xor(part, 32);            // combine the two halves
  if (lane < 16)      xl2[(size_t)node * 16 + j]        = part + b2s[j];
  else if (lane < 32) xr2[(size_t)node * 16 + (j - 16)] = part + b2s[j];
}

// ---------------- Fused layer 2 (round-4 version: separate dense xl/xr) -------
__global__ void fused_layer2(const int* __restrict__ row_start, const int* __restrict__ csr_src,
                             const float* __restrict__ xl, const float* __restrict__ xr,
                             const float* __restrict__ att, const float* __restrict__ bias,
                             float* __restrict__ out, int n) {
  int node = blockIdx.x * 16 + (threadIdx.x >> 4);
  if (node >= n) return;
  int c = threadIdx.x & 15;
  const float attv = att[c];
  const float xrv  = xr[(size_t)node * 16 + c];
  const int beg = row_start[node], end = row_start[node + 1];
  float m = -__builtin_huge_valf();
  float den = 0.0f, acc = 0.0f;
  int p = beg;
  for (; p + 4 <= end; p += 4) {
    int s0 = csr_src[p + 0], s1 = csr_src[p + 1];
    int s2 = csr_src[p + 2], s3 = csr_src[p + 3];
    float x0 = xl[(size_t)s0 * 16 + c];
    float x1 = xl[(size_t)s1 * 16 + c];
    float x2 = xl[(size_t)s2 * 16 + c];
    float x3 = xl[(size_t)s3 * 16 + c];
    float a0 = x0 + xrv; a0 = a0 > 0.f ? a0 : 0.2f * a0;
    float a1 = x1 + xrv; a1 = a1 > 0.f ? a1 : 0.2f * a1;
    float a2 = x2 + xrv; a2 = a2 > 0.f ? a2 : 0.2f * a2;
    float a3 = x3 + xrv; a3 = a3 > 0.f ? a3 : 0.2f * a3;
    float v0 = sum16_dpp(a0 * attv);
    float v1 = sum16_dpp(a1 * attv);
    float v2 = sum16_dpp(a2 * attv);
    float v3 = sum16_dpp(a3 * attv);
    float nm = fmaxf(m, fmaxf(fmaxf(v0, v1), fmaxf(v2, v3)));
    float scale = __expf(m - nm);
    float e0 = __expf(v0 - nm), e1 = __expf(v1 - nm);
    float e2 = __expf(v2 - nm), e3 = __expf(v3 - nm);
    den = den * scale + ((e0 + e1) + (e2 + e3));
    acc = acc * scale + ((e0 * x0 + e1 * x1) + (e2 * x2 + e3 * x3));
    m = nm;
  }
  for (; p < end; ++p) {
    int s = csr_src[p];
    float xv = xl[(size_t)s * 16 + c];
    float a = xv + xrv; a = a > 0.f ? a : 0.2f * a;
    float v = sum16_dpp(a * attv);
    float nm = fmaxf(m, v);
    float scale = __expf(m - nm);
    float ex = __expf(v - nm);
    den = den * scale + ex;
    acc = acc * scale + ex * xv;
    m = nm;
  }
  out[(size_t)node * 16 + c] = acc / (den + 1e-16f) + bias[c];   // no elu after conv2
}

// ---------------- Pooling + classifier ---------------------------------------

__global__ void pool_kernel(const float* __restrict__ h2, const int* __restrict__ batch,
                            float* __restrict__ sums, float* __restrict__ cnts, int n) {
  __shared__ float ls[NB * CH2_];
  __shared__ float lc[NB];
  for (int i = threadIdx.x; i < NB * CH2_; i += blockDim.x) ls[i] = 0.0f;
  for (int i = threadIdx.x; i < NB; i += blockDim.x) lc[i] = 0.0f;
  __syncthreads();
  int total = n * 16;
  int stride = gridDim.x * blockDim.x;
  for (int i = blockIdx.x * blockDim.x + threadIdx.x; i < total; i += stride) {
    int node = i >> 4, c = i & 15;
    int b = batch[node];
    atomicAdd(&ls[b * 16 + c], h2[i]);
    if (c == 0) atomicAdd(&lc[b], 1.0f);
  }
  __syncthreads();
  for (int i = threadIdx.x; i < NB * CH2_; i += blockDim.x)
    if (ls[i] != 0.0f) atomicAdd(&sums[i], ls[i]);
  for (int i = threadIdx.x; i < NB; i += blockDim.x)
    if (lc[i] != 0.0f) atomicAdd(&cnts[i], lc[i]);
}

__global__ void classifier(const float* __restrict__ sums, const float* __restrict__ cnts,
                           const float* __restrict__ Wc, const float* __restrict__ bc,
                           float* __restrict__ out) {
  int b = threadIdx.x;
  if (b >= NB) return;
  float cnt = cnts[b];
  cnt = cnt > 1.0f ? cnt : 1.0f;
  float acc = 0.0f;
  for (int c = 0; c < 16; ++c) {
    float p = sums[b * 16 + c] / cnt;
    out[NB + b * 16 + c] = p;   // pooled, output 1
    acc += p * Wc[c];
  }
  out[b] = acc + bc[0];         // out, output 0
}

extern "C" void kernel_launch(void* const* d_in, const int* in_sizes, int n_in,
                              void* d_out, int out_size, void* d_ws, size_t ws_size,
                              hipStream_t stream) {
  const float* x     = (const float*)d_in[0];
  const int*   ei    = (const int*)d_in[1];
  const int*   batch = (const int*)d_in[2];
  const float* Wl1   = (const float*)d_in[3];
  const float* bl1   = (const float*)d_in[4];
  const float* Wr1   = (const float*)d_in[5];
  const float* br1   = (const float*)d_in[6];
  const float* att1  = (const float*)d_in[7];
  const float* bias1 = (const float*)d_in[8];
  const float* Wl2   = (const float*)d_in[9];
  const float* bl2   = (const float*)d_in[10];
  const float* Wr2   = (const float*)d_in[11];
  const float* br2   = (const float*)d_in[12];
  const float* att2  = (const float*)d_in[13];
  const float* bias2 = (const float*)d_in[14];
  const float* Wc    = (const float*)d_in[15];
  const float* bc    = (const float*)d_in[16];
  float* out = (float*)d_out;

  const int N  = in_sizes[0] / F_IN;
  const int E  = in_sizes[1] / 2;
  const int E2 = E + N;
  const int nblk = (N + 255) / 256;

  // Workspace layout (no overlays; ~78 MB total)
  float* ws   = (float*)d_ws;
  float* xl1  = ws;                            // N*64
  float* xr1  = xl1 + (size_t)N * 64;          // N*64
  float* xl2  = xr1 + (size_t)N * 64;          // N*16
  float* xr2  = xl2 + (size_t)N * 16;          // N*16
  float* h2   = xr2 + (size_t)N * 16;          // N*16
  int* ideg   = (int*)(h2 + (size_t)N * 16);   // N
  int* icnt   = ideg + N;                      // N
  int* irow   = icnt + N;                      // N+1
  int* ipart  = irow + (N + 1);                // nblk
  int* icsr   = ipart + ((nblk + 63) & ~63);   // E2
  float* sums = (float*)(icsr + E2);           // NB*16
  float* cnts = sums + NB * CH2_;              // NB

  // ---- CSR build (shared by both layers) ----
  fill_f32<<<256, 256, 0, stream>>>((float*)ideg, 0.0f, 2 * N);   // deg + cnt = 0
  hist_kernel<<<(E2 + 255) / 256, 256, 0, stream>>>(ei, E, E2, ideg);
  scan_partials<<<nblk, 256, 0, stream>>>(ideg, ipart, N);
  scan_block<<<1, 64, 0, stream>>>(ipart, nblk, irow, N);
  scan_final<<<nblk, 256, 0, stream>>>(ideg, ipart, irow, N);
  scatter_kernel<<<(E2 + 255) / 256, 256, 0, stream>>>(ei, E, E2, irow, icnt, icsr);

  // ---- layer 1 GEMM ----
  gemm_dual<F_IN, HC1, 64, false><<<(N + 63) / 64, 256, 0, stream>>>(
      x, Wl1, bl1, Wr1, br1, xl1, xr1, N);

  // ---- fused layer 1 + layer-2 linear transforms ----
  fused_layer1<<<(N + 3) / 4, 256, 0, stream>>>(
      irow, icsr, xl1, xr1, att1, bias1, Wl2, bl2, Wr2, br2, xl2, xr2, N);

  // ---- fused layer 2 ----
  fused_layer2<<<(N + 15) / 16, 256, 0, stream>>>(irow, icsr, xl2, xr2, att2, bias2, h2, N);

  // ---- pooling + classifier ----
  fill_f32<<<4, 256, 0, stream>>>(sums, 0.0f, NB * CH2_ + NB);
  pool_kernel<<<256, 256, 0, stream>>>(h2, batch, sums, cnts, N);
  classifier<<<1, 64, 0, stream>>>(sums, cnts, Wc, bc, out);
}

// Round 7
// 288.566 us; speedup vs baseline: 2.4079x; 1.4776x over previous
//
#include <hip/hip_runtime.h>
#include <cstdint>
#include <cstddef>

// Problem constants (shapes fixed by the reference)
#define F_IN   128
#define HC1    64    // heads1*ch1 = 8*8
#define CH2_   16
#define NB     64    // batch graphs
#define BUKPAD 8192  // per-bucket padding (avg fill ~4350 for E=1.6M, N=100K)

__global__ void fill_f32(float* __restrict__ p, float v, int n) {
  int i = blockIdx.x * blockDim.x + threadIdx.x;
  int stride = gridDim.x * blockDim.x;
  for (; i < n; i += stride) p[i] = v;
}

// ---------------- DPP cross-lane reductions (full-rate VALU, no LDS pipe) -----
template<int CTRL>
__device__ __forceinline__ float dpp_add(float v) {
  int j = __builtin_amdgcn_update_dpp(0, __float_as_int(v), CTRL, 0xF, 0xF, true);
  return v + __int_as_float(j);
}
__device__ __forceinline__ float sum8_dpp(float v) {   // sum over each 8-lane group
  v = dpp_add<0xB1>(v);   // quad_perm xor1
  v = dpp_add<0x4E>(v);   // quad_perm xor2
  v = dpp_add<0x141>(v);  // row_half_mirror
  return v;
}
__device__ __forceinline__ float sum16_dpp(float v) {  // sum over each 16-lane row
  v = dpp_add<0xB1>(v);
  v = dpp_add<0x4E>(v);
  v = dpp_add<0x141>(v);
  v = dpp_add<0x140>(v);  // row_mirror
  return v;
}

// ---------------- Layer-1 dual GEMM (M=64): known-good round-4 version --------
template<int K, int M, int BM, bool PAD>
__global__ void gemm_dual(const float* __restrict__ x,
                          const float* __restrict__ Wa, const float* __restrict__ ba,
                          const float* __restrict__ Wb, const float* __restrict__ bb,
                          float* __restrict__ ya, float* __restrict__ yb, int n) {
  constexpr int KP = PAD ? K + 4 : K;
  constexpr int GROUPS = 256 / M;
  constexpr int NN = BM / GROUPS;
  __shared__ float xs[BM * KP];
  const int t = threadIdx.x;
  const int node0 = blockIdx.x * BM;
  for (int i = t; i < BM * (K / 4); i += 256) {
    int row = i / (K / 4);
    int kk  = (i % (K / 4)) * 4;
    int node = node0 + row;
    float4 v = make_float4(0.f, 0.f, 0.f, 0.f);
    if (node < n) v = *reinterpret_cast<const float4*>(x + (size_t)node * K + kk);
    *reinterpret_cast<float4*>(xs + row * KP + kk) = v;
  }
  __syncthreads();
  const int col = t % M;
  const int ng  = t / M;
  float accA[NN], accB[NN];
  const float biasA = ba[col], biasB = bb[col];
#pragma unroll
  for (int i = 0; i < NN; ++i) { accA[i] = biasA; accB[i] = biasB; }
  for (int k = 0; k < K; k += 4) {
    float wa0 = Wa[(k + 0) * M + col], wa1 = Wa[(k + 1) * M + col];
    float wa2 = Wa[(k + 2) * M + col], wa3 = Wa[(k + 3) * M + col];
    float wb0 = Wb[(k + 0) * M + col], wb1 = Wb[(k + 1) * M + col];
    float wb2 = Wb[(k + 2) * M + col], wb3 = Wb[(k + 3) * M + col];
#pragma unroll
    for (int nn = 0; nn < NN; ++nn) {
      float4 xv = *reinterpret_cast<const float4*>(xs + (ng * NN + nn) * KP + k);
      accA[nn] += xv.x * wa0 + xv.y * wa1 + xv.z * wa2 + xv.w * wa3;
      accB[nn] += xv.x * wb0 + xv.y * wb1 + xv.z * wb2 + xv.w * wb3;
    }
  }
#pragma unroll
  for (int nn = 0; nn < NN; ++nn) {
    int node = node0 + ng * NN + nn;
    if (node < n) {
      ya[(size_t)node * M + col] = accA[nn];
      yb[(size_t)node * M + col] = accB[nn];
    }
  }
}

// ---------------- CSR build via 2-pass bucketed counting sort -----------------
// Round-6 scatter_kernel burned 109MB of HBM writes (64B line per random 4B
// store). Pass 1 groups edges into 256-node buckets with (block,bucket)
// contiguous runs (avg ~21 entries = 84B -> ~1.5x amp). Pass 2 builds the
// exact CSR inside each bucket's contiguous ~17KB window (L2-resident).

// Pass 1: tile=8192 edges/block; LDS hist over buckets; reserve runs; write
// packed (src<<8 | dst&255).
__global__ void bucket_scatter(const int* __restrict__ ei, int E, int E2,
                               int* __restrict__ gcnt, int* __restrict__ gbuk) {
  __shared__ int hbase[512];
  __shared__ int hcnt[512];
  const int t = threadIdx.x;
  for (int i = t; i < 512; i += 256) { hbase[i] = 0; hcnt[i] = 0; }
  __syncthreads();
  int srcs[32], dsts[32];
  const int tile0 = blockIdx.x * 8192;
#pragma unroll
  for (int k = 0; k < 32; ++k) {
    int e = tile0 + k * 256 + t;          // coalesced
    int s = -1, d = 0;
    if (e < E2) {
      if (e < E) { s = ei[e]; d = ei[E + e]; } else { s = d = e - E; }
      atomicAdd(&hbase[d >> 8], 1);       // LDS atomic
    }
    srcs[k] = s; dsts[k] = d;
  }
  __syncthreads();
  for (int i = t; i < 512; i += 256) {    // reserve this block's run per bucket
    int c = hbase[i];
    hbase[i] = (c > 0) ? atomicAdd(&gcnt[i], c) : 0;
  }
  __syncthreads();
#pragma unroll
  for (int k = 0; k < 32; ++k) {
    if (srcs[k] >= 0) {
      int d = dsts[k], b = d >> 8;
      int r = atomicAdd(&hcnt[b], 1);     // LDS atomic: rank within (block,bucket)
      int pl = hbase[b] + r;
      if (pl < BUKPAD) gbuk[(size_t)b * BUKPAD + pl] = (srcs[k] << 8) | (d & 255);
    }
  }
}

// Exclusive scan over bucket counts -> per-bucket CSR base (single wave)
__global__ void bucket_prefix(const int* __restrict__ gcnt, int nbuk,
                              int* __restrict__ gbase, int* __restrict__ row_start, int n) {
  int lane = threadIdx.x;  // 64 threads
  int carry = 0;
  for (int basei = 0; basei < nbuk; basei += 64) {
    int i = basei + lane;
    int orig = (i < nbuk) ? gcnt[i] : 0;
    int v = orig;
    for (int off = 1; off < 64; off <<= 1) {
      int u = __shfl_up(v, off);
      if (lane >= off) v += u;
    }
    if (i < nbuk) gbase[i] = carry + v - orig;
    carry += __shfl(v, 63);
  }
  if (lane == 0) row_start[n] = carry;    // == E2
}

// Pass 2: one block per bucket; per-node hist+scan in LDS; scatter src into
// the bucket's contiguous csr window; emit row_start coalesced.
__global__ void bucket_csr(const int* __restrict__ gcnt, const int* __restrict__ gbase,
                           const int* __restrict__ gbuk,
                           int* __restrict__ row_start, int* __restrict__ csr_src, int n) {
  const int b = blockIdx.x;
  const int t = threadIdx.x;
  const int node0 = b << 8;
  const int cntb = min(gcnt[b], BUKPAD);
  const int base = gbase[b];
  const int* buk = gbuk + (size_t)b * BUKPAD;
  __shared__ int h[256];
  __shared__ int off[256];
  h[t] = 0;
  __syncthreads();
  for (int i = t; i < cntb; i += 256) atomicAdd(&h[buk[i] & 255], 1);
  __syncthreads();
  off[t] = h[t];
  __syncthreads();
  for (int o = 1; o < 256; o <<= 1) {     // inclusive Hillis-Steele scan
    int u = (t >= o) ? off[t - o] : 0;
    __syncthreads();
    off[t] += u;
    __syncthreads();
  }
  int excl = off[t] - h[t];
  if (node0 + t < n) row_start[node0 + t] = base + excl;
  h[t] = excl;                            // running counter per node
  __syncthreads();
  for (int i = t; i < cntb; i += 256) {
    int p = buk[i];
    int r = atomicAdd(&h[p & 255], 1);    // LDS atomic
    csr_src[base + r] = p >> 8;           // store within ~17KB L2-hot window
  }
}

// ---------------- Fused layer 1 + layer-2 linear transforms -------------------
__global__ void fused_layer1(const int* __restrict__ row_start, const int* __restrict__ csr_src,
                             const float* __restrict__ xl, const float* __restrict__ xr,
                             const float* __restrict__ att, const float* __restrict__ bias,
                             const float* __restrict__ Wl2, const float* __restrict__ bl2,
                             const float* __restrict__ Wr2, const float* __restrict__ br2,
                             float* __restrict__ xl2, float* __restrict__ xr2, int n) {
  __shared__ float Ws2[64 * 32];   // [l][j]: j<16 -> Wl2 col j, j>=16 -> Wr2 col j-16
  __shared__ float b2s[32];
  const int t = threadIdx.x;
  for (int i = t; i < 64 * 16; i += 256) {
    int l = i >> 4, j = i & 15;
    Ws2[l * 32 + j]      = Wl2[i];
    Ws2[l * 32 + 16 + j] = Wr2[i];
  }
  if (t < 16) { b2s[t] = bl2[t]; b2s[16 + t] = br2[t]; }
  __syncthreads();

  int node = blockIdx.x * 4 + (t >> 6);
  if (node >= n) return;
  int lane = t & 63;
  const float attv = att[lane];
  const float xrv  = xr[(size_t)node * 64 + lane];
  const int beg = row_start[node], end = row_start[node + 1];
  float m = -__builtin_huge_valf();
  float den = 0.0f, acc = 0.0f;
  int p = beg;
  for (; p + 4 <= end; p += 4) {
    int s0 = csr_src[p + 0], s1 = csr_src[p + 1];
    int s2 = csr_src[p + 2], s3 = csr_src[p + 3];
    float x0 = xl[(size_t)s0 * 64 + lane];
    float x1 = xl[(size_t)s1 * 64 + lane];
    float x2 = xl[(size_t)s2 * 64 + lane];
    float x3 = xl[(size_t)s3 * 64 + lane];
    float a0 = x0 + xrv; a0 = a0 > 0.f ? a0 : 0.2f * a0;
    float a1 = x1 + xrv; a1 = a1 > 0.f ? a1 : 0.2f * a1;
    float a2 = x2 + xrv; a2 = a2 > 0.f ? a2 : 0.2f * a2;
    float a3 = x3 + xrv; a3 = a3 > 0.f ? a3 : 0.2f * a3;
    float v0 = sum8_dpp(a0 * attv);
    float v1 = sum8_dpp(a1 * attv);
    float v2 = sum8_dpp(a2 * attv);
    float v3 = sum8_dpp(a3 * attv);
    float nm = fmaxf(m, fmaxf(fmaxf(v0, v1), fmaxf(v2, v3)));
    float scale = __expf(m - nm);          // first chunk: exp(-inf)=0
    float e0 = __expf(v0 - nm), e1 = __expf(v1 - nm);
    float e2 = __expf(v2 - nm), e3 = __expf(v3 - nm);
    den = den * scale + ((e0 + e1) + (e2 + e3));
    acc = acc * scale + ((e0 * x0 + e1 * x1) + (e2 * x2 + e3 * x3));
    m = nm;
  }
  for (; p < end; ++p) {
    int s = csr_src[p];
    float xv = xl[(size_t)s * 64 + lane];
    float a = xv + xrv; a = a > 0.f ? a : 0.2f * a;
    float v = sum8_dpp(a * attv);
    float nm = fmaxf(m, v);
    float scale = __expf(m - nm);
    float ex = __expf(v - nm);
    den = den * scale + ex;
    acc = acc * scale + ex * xv;
    m = nm;
  }
  float o = acc / (den + 1e-16f) + bias[lane];
  o = o > 0.0f ? o : (__expf(o) - 1.0f);   // elu -> h1 value for col=lane

  // in-wave layer-2 transforms: out[j] = sum_l o_l * Ws2[l][j]
  const int j    = lane & 31;
  const int half = lane >> 5;              // 0: l=0..31, 1: l=32..63
  float part = 0.0f;
#pragma unroll 8
  for (int l = 0; l < 32; ++l) {
    int src = half * 32 + l;
    float ov = __shfl(o, src);
    part += ov * Ws2[src * 32 + j];
  }
  part += __shfl_xor(part, 32);            // combine the two halves
  if (lane < 16)      xl2[(size_t)node * 16 + j]        = part + b2s[j];
  else if (lane < 32) xr2[(size_t)node * 16 + (j - 16)] = part + b2s[j];
}

// ---------------- Fused layer 2 ----------------------------------------------
__global__ void fused_layer2(const int* __restrict__ row_start, const int* __restrict__ csr_src,
                             const float* __restrict__ xl, const float* __restrict__ xr,
                             const float* __restrict__ att, const float* __restrict__ bias,
                             float* __restrict__ out, int n) {
  int node = blockIdx.x * 16 + (threadIdx.x >> 4);
  if (node >= n) return;
  int c = threadIdx.x & 15;
  const float attv = att[c];
  const float xrv  = xr[(size_t)node * 16 + c];
  const int beg = row_start[node], end = row_start[node + 1];
  float m = -__builtin_huge_valf();
  float den = 0.0f, acc = 0.0f;
  int p = beg;
  for (; p + 4 <= end; p += 4) {
    int s0 = csr_src[p + 0], s1 = csr_src[p + 1];
    int s2 = csr_src[p + 2], s3 = csr_src[p + 3];
    float x0 = xl[(size_t)s0 * 16 + c];
    float x1 = xl[(size_t)s1 * 16 + c];
    float x2 = xl[(size_t)s2 * 16 + c];
    float x3 = xl[(size_t)s3 * 16 + c];
    float a0 = x0 + xrv; a0 = a0 > 0.f ? a0 : 0.2f * a0;
    float a1 = x1 + xrv; a1 = a1 > 0.f ? a1 : 0.2f * a1;
    float a2 = x2 + xrv; a2 = a2 > 0.f ? a2 : 0.2f * a2;
    float a3 = x3 + xrv; a3 = a3 > 0.f ? a3 : 0.2f * a3;
    float v0 = sum16_dpp(a0 * attv);
    float v1 = sum16_dpp(a1 * attv);
    float v2 = sum16_dpp(a2 * attv);
    float v3 = sum16_dpp(a3 * attv);
    float nm = fmaxf(m, fmaxf(fmaxf(v0, v1), fmaxf(v2, v3)));
    float scale = __expf(m - nm);
    float e0 = __expf(v0 - nm), e1 = __expf(v1 - nm);
    float e2 = __expf(v2 - nm), e3 = __expf(v3 - nm);
    den = den * scale + ((e0 + e1) + (e2 + e3));
    acc = acc * scale + ((e0 * x0 + e1 * x1) + (e2 * x2 + e3 * x3));
    m = nm;
  }
  for (; p < end; ++p) {
    int s = csr_src[p];
    float xv = xl[(size_t)s * 16 + c];
    float a = xv + xrv; a = a > 0.f ? a : 0.2f * a;
    float v = sum16_dpp(a * attv);
    float nm = fmaxf(m, v);
    float scale = __expf(m - nm);
    float ex = __expf(v - nm);
    den = den * scale + ex;
    acc = acc * scale + ex * xv;
    m = nm;
  }
  out[(size_t)node * 16 + c] = acc / (den + 1e-16f) + bias[c];   // no elu after conv2
}

// ---------------- Pooling + classifier ---------------------------------------

__global__ void pool_kernel(const float* __restrict__ h2, const int* __restrict__ batch,
                            float* __restrict__ sums, float* __restrict__ cnts, int n) {
  __shared__ float ls[NB * CH2_];
  __shared__ float lc[NB];
  for (int i = threadIdx.x; i < NB * CH2_; i += blockDim.x) ls[i] = 0.0f;
  for (int i = threadIdx.x; i < NB; i += blockDim.x) lc[i] = 0.0f;
  __syncthreads();
  int total = n * 16;
  int stride = gridDim.x * blockDim.x;
  for (int i = blockIdx.x * blockDim.x + threadIdx.x; i < total; i += stride) {
    int node = i >> 4, c = i & 15;
    int b = batch[node];
    atomicAdd(&ls[b * 16 + c], h2[i]);
    if (c == 0) atomicAdd(&lc[b], 1.0f);
  }
  __syncthreads();
  for (int i = threadIdx.x; i < NB * CH2_; i += blockDim.x)
    if (ls[i] != 0.0f) atomicAdd(&sums[i], ls[i]);
  for (int i = threadIdx.x; i < NB; i += blockDim.x)
    if (lc[i] != 0.0f) atomicAdd(&cnts[i], lc[i]);
}

__global__ void classifier(const float* __restrict__ sums, const float* __restrict__ cnts,
                           const float* __restrict__ Wc, const float* __restrict__ bc,
                           float* __restrict__ out) {
  int b = threadIdx.x;
  if (b >= NB) return;
  float cnt = cnts[b];
  cnt = cnt > 1.0f ? cnt : 1.0f;
  float acc = 0.0f;
  for (int c = 0; c < 16; ++c) {
    float p = sums[b * 16 + c] / cnt;
    out[NB + b * 16 + c] = p;   // pooled, output 1
    acc += p * Wc[c];
  }
  out[b] = acc + bc[0];         // out, output 0
}

extern "C" void kernel_launch(void* const* d_in, const int* in_sizes, int n_in,
                              void* d_out, int out_size, void* d_ws, size_t ws_size,
                              hipStream_t stream) {
  const float* x     = (const float*)d_in[0];
  const int*   ei    = (const int*)d_in[1];
  const int*   batch = (const int*)d_in[2];
  const float* Wl1   = (const float*)d_in[3];
  const float* bl1   = (const float*)d_in[4];
  const float* Wr1   = (const float*)d_in[5];
  const float* br1   = (const float*)d_in[6];
  const float* att1  = (const float*)d_in[7];
  const float* bias1 = (const float*)d_in[8];
  const float* Wl2   = (const float*)d_in[9];
  const float* bl2   = (const float*)d_in[10];
  const float* Wr2   = (const float*)d_in[11];
  const float* br2   = (const float*)d_in[12];
  const float* att2  = (const float*)d_in[13];
  const float* bias2 = (const float*)d_in[14];
  const float* Wc    = (const float*)d_in[15];
  const float* bc    = (const float*)d_in[16];
  float* out = (float*)d_out;

  const int N  = in_sizes[0] / F_IN;
  const int E  = in_sizes[1] / 2;
  const int E2 = E + N;
  const int nbuk = (N + 255) >> 8;   // 391 for N=100K (<=512 assumed)

  // Workspace layout (~90 MB)
  float* ws   = (float*)d_ws;
  float* xl1  = ws;                            // N*64
  float* xr1  = xl1 + (size_t)N * 64;          // N*64
  float* xl2  = xr1 + (size_t)N * 64;          // N*16
  float* xr2  = xl2 + (size_t)N * 16;          // N*16
  float* h2   = xr2 + (size_t)N * 16;          // N*16
  int* irow   = (int*)(h2 + (size_t)N * 16);   // N+1
  int* icsr   = irow + (N + 1);                // E2
  int* gcnt   = icsr + E2;                     // 512
  int* gbase  = gcnt + 512;                    // 512+1
  int* gbuk   = gbase + 513 + 2;               // nbuk*BUKPAD
  float* sums = (float*)(gbuk + (size_t)nbuk * BUKPAD);  // NB*16
  float* cnts = sums + NB * CH2_;              // NB

  // ---- CSR build (2-pass bucketed counting sort) ----
  fill_f32<<<1, 256, 0, stream>>>((float*)gcnt, 0.0f, 512);
  bucket_scatter<<<(E2 + 8191) / 8192, 256, 0, stream>>>(ei, E, E2, gcnt, gbuk);
  bucket_prefix<<<1, 64, 0, stream>>>(gcnt, nbuk, gbase, irow, N);
  bucket_csr<<<nbuk, 256, 0, stream>>>(gcnt, gbase, gbuk, irow, icsr, N);

  // ---- layer 1 GEMM ----
  gemm_dual<F_IN, HC1, 64, false><<<(N + 63) / 64, 256, 0, stream>>>(
      x, Wl1, bl1, Wr1, br1, xl1, xr1, N);

  // ---- fused layer 1 + layer-2 linear transforms ----
  fused_layer1<<<(N + 3) / 4, 256, 0, stream>>>(
      irow, icsr, xl1, xr1, att1, bias1, Wl2, bl2, Wr2, br2, xl2, xr2, N);

  // ---- fused layer 2 ----
  fused_layer2<<<(N + 15) / 16, 256, 0, stream>>>(irow, icsr, xl2, xr2, att2, bias2, h2, N);

  // ---- pooling + classifier ----
  fill_f32<<<1, 256, 0, stream>>>(sums, 0.0f, NB * CH2_ + NB);
  pool_kernel<<<256, 256, 0, stream>>>(h2, batch, sums, cnts, N);
  classifier<<<1, 64, 0, stream>>>(sums, cnts, Wc, bc, out);
}